// Round 1
// baseline (653.328 us; speedup 1.0000x reference)
//
#include <hip/hip_runtime.h>
#include <hip/hip_bf16.h>
#include <stdint.h>

typedef __attribute__((ext_vector_type(8))) short short8;
typedef __attribute__((ext_vector_type(4))) float f32x4;
typedef unsigned short u16;

#define B_  2
#define T_  2048
#define D_  1024
#define H_  16
#define DH_ 64

__device__ __forceinline__ u16 f2bf(float x) {
    union { float f; uint32_t u; } v; v.f = x;
    uint32_t r = v.u + 0x7fffu + ((v.u >> 16) & 1u);
    return (u16)(r >> 16);
}
__device__ __forceinline__ float bf2f(u16 h) {
    union { uint32_t u; float f; } v; v.u = ((uint32_t)h) << 16;
    return v.f;
}
__device__ __forceinline__ f32x4 mfma16(short8 a, short8 b, f32x4 c) {
    return __builtin_amdgcn_mfma_f32_16x16x32_bf16(a, b, c, 0, 0, 0);
}

// ---------------------------------------------------------------------------
// Kernel 1: QKV projections.  C = X @ W + bias (then *scale for Q).
// z=0 -> Q (hi/lo, scaled 1/8), z=1 -> K (hi/lo), z=2 -> V (hi only, transposed)
// Q,K layout: [B,H,T,64] bf16 hi + bf16 lo.  V layout: [B,H,64,T] bf16.
// Split-bf16 (3-term) GEMM => effectively fp32-accurate projections.
// ---------------------------------------------------------------------------
__global__ __launch_bounds__(256) void qkv_proj_kernel(
    const float* __restrict__ X,
    const float* __restrict__ Wq, const float* __restrict__ bq,
    const float* __restrict__ Wk, const float* __restrict__ bk,
    const float* __restrict__ Wv, const float* __restrict__ bv,
    u16* __restrict__ Qhi, u16* __restrict__ Qlo,
    u16* __restrict__ Khi, u16* __restrict__ Klo,
    u16* __restrict__ Vt)
{
    __shared__ u16 s_ahi[64 * 32];
    __shared__ u16 s_alo[64 * 32];
    __shared__ u16 s_bhi[64 * 32];   // transposed: [n][k]
    __shared__ u16 s_blo[64 * 32];

    const int z = blockIdx.z;
    const float* __restrict__ W   = (z == 0) ? Wq : (z == 1) ? Wk : Wv;
    const float* __restrict__ bia = (z == 0) ? bq : (z == 1) ? bk : bv;
    const float scale = (z == 0) ? 0.125f : 1.0f;   // dh^-0.5 = 1/8

    const int m0 = blockIdx.y * 64;
    const int n0 = blockIdx.x * 64;
    const int tid  = threadIdx.x;
    const int w    = tid >> 6;
    const int lane = tid & 63;
    const int g    = lane >> 4;
    const int lr   = lane & 15;
    const int wr = (w >> 1) * 32, wc = (w & 1) * 32;

    const int ar = tid >> 2, ak = (tid & 3) * 8;   // A stage: 64 rows x 32 k
    const int br = tid >> 3, bn = (tid & 7) * 8;   // W stage: 32 k x 64 n

    f32x4 acc[2][2] = {};

    for (int k0 = 0; k0 < D_; k0 += 32) {
        float4 a0 = *(const float4*)(X + (size_t)(m0 + ar) * D_ + k0 + ak);
        float4 a1 = *(const float4*)(X + (size_t)(m0 + ar) * D_ + k0 + ak + 4);
        float4 b0 = *(const float4*)(W + (size_t)(k0 + br) * D_ + n0 + bn);
        float4 b1 = *(const float4*)(W + (size_t)(k0 + br) * D_ + n0 + bn + 4);
        float av[8] = {a0.x, a0.y, a0.z, a0.w, a1.x, a1.y, a1.z, a1.w};
        float bw[8] = {b0.x, b0.y, b0.z, b0.w, b1.x, b1.y, b1.z, b1.w};

        __syncthreads();   // previous iteration's LDS reads done
#pragma unroll
        for (int i = 0; i < 8; ++i) {
            u16 h = f2bf(av[i]);
            s_ahi[ar * 32 + ak + i] = h;
            s_alo[ar * 32 + ak + i] = f2bf(av[i] - bf2f(h));
        }
#pragma unroll
        for (int i = 0; i < 8; ++i) {
            u16 h = f2bf(bw[i]);
            s_bhi[(bn + i) * 32 + br] = h;
            s_blo[(bn + i) * 32 + br] = f2bf(bw[i] - bf2f(h));
        }
        __syncthreads();

        short8 ah[2], al[2], bh[2], bl[2];
#pragma unroll
        for (int f = 0; f < 2; ++f) {
            ah[f] = *(const short8*)&s_ahi[(wr + f * 16 + lr) * 32 + g * 8];
            al[f] = *(const short8*)&s_alo[(wr + f * 16 + lr) * 32 + g * 8];
            bh[f] = *(const short8*)&s_bhi[(wc + f * 16 + lr) * 32 + g * 8];
            bl[f] = *(const short8*)&s_blo[(wc + f * 16 + lr) * 32 + g * 8];
        }
#pragma unroll
        for (int fm = 0; fm < 2; ++fm)
#pragma unroll
            for (int fn = 0; fn < 2; ++fn) {
                acc[fm][fn] = mfma16(ah[fm], bh[fn], acc[fm][fn]);
                acc[fm][fn] = mfma16(ah[fm], bl[fn], acc[fm][fn]);
                acc[fm][fn] = mfma16(al[fm], bh[fn], acc[fm][fn]);
            }
    }

    // Epilogue: C/D layout col=lane&15, row=(lane>>4)*4+j  [HW-verified]
#pragma unroll
    for (int fm = 0; fm < 2; ++fm)
#pragma unroll
        for (int fn = 0; fn < 2; ++fn)
#pragma unroll
            for (int j = 0; j < 4; ++j) {
                int r = m0 + wr + fm * 16 + g * 4 + j;
                int c = n0 + wc + fn * 16 + lr;
                float v = (acc[fm][fn][j] + bia[c]) * scale;
                int b = r >> 11, t = r & (T_ - 1);
                int h = c >> 6,  d = c & 63;
                if (z == 2) {
                    Vt[((size_t)(b * H_ + h) * DH_ + d) * T_ + t] = f2bf(v);
                } else {
                    size_t idx = ((size_t)(b * H_ + h) * T_ + t) * DH_ + d;
                    u16 hv = f2bf(v);
                    u16 lv = f2bf(v - bf2f(hv));
                    if (z == 0) { Qhi[idx] = hv; Qlo[idx] = lv; }
                    else        { Khi[idx] = hv; Klo[idx] = lv; }
                }
            }
}

// ---------------------------------------------------------------------------
// Kernel 2: flash attention with mask.  1 block = (b, h, 64 q-rows); 4 waves,
// each wave owns 16 q-rows.  KV tiles of 32.  QK^T split-bf16 (3 terms),
// PV plain bf16.  Online softmax, masked logits = -1e30.
// ---------------------------------------------------------------------------
__global__ __launch_bounds__(256) void attn_kernel(
    const u16* __restrict__ Qhi, const u16* __restrict__ Qlo,
    const u16* __restrict__ Khi, const u16* __restrict__ Klo,
    const u16* __restrict__ Vt,  const int* __restrict__ mask,
    u16* __restrict__ comb)
{
    __shared__ u16 p_lds[4][16 * 32];   // per-wave P transpose buffer

    const int bx = blockIdx.x;
    const int qb = bx & 31;            // 32 q-tiles of 64
    const int bh = bx >> 5;
    const int b = bh >> 4, h = bh & 15;
    const int tid  = threadIdx.x;
    const int w    = tid >> 6;
    const int lane = tid & 63;
    const int g    = lane >> 4;
    const int lr   = lane & 15;
    const int qt0  = qb * 64 + w * 16;  // wave's q-strip base

    const size_t hoff = (size_t)(b * H_ + h) * T_ * DH_;
    const u16* Qh = Qhi + hoff;
    const u16* Ql = Qlo + hoff;
    const u16* Kh = Khi + hoff;
    const u16* Kl = Klo + hoff;
    const u16* Vh = Vt + hoff;          // [64][2048]
    const int* mbase = mask + (size_t)b * T_ * T_;

    short8 qh[2], ql[2];
#pragma unroll
    for (int ks = 0; ks < 2; ++ks) {
        qh[ks] = *(const short8*)&Qh[(size_t)(qt0 + lr) * DH_ + ks * 32 + g * 8];
        ql[ks] = *(const short8*)&Ql[(size_t)(qt0 + lr) * DH_ + ks * 32 + g * 8];
    }

    f32x4 o[4] = {};
    float m_run[4] = {-1e30f, -1e30f, -1e30f, -1e30f};
    float l_run[4] = {0.f, 0.f, 0.f, 0.f};
    const float L2E = 1.4426950408889634f;

    for (int kv0 = 0; kv0 < T_; kv0 += 32) {
        f32x4 s[2] = {};
#pragma unroll
        for (int f = 0; f < 2; ++f)
#pragma unroll
            for (int ks = 0; ks < 2; ++ks) {
                short8 kh = *(const short8*)&Kh[(size_t)(kv0 + f * 16 + lr) * DH_ + ks * 32 + g * 8];
                short8 kl = *(const short8*)&Kl[(size_t)(kv0 + f * 16 + lr) * DH_ + ks * 32 + g * 8];
                s[f] = mfma16(qh[ks], kh, s[f]);
                s[f] = mfma16(qh[ks], kl, s[f]);
                s[f] = mfma16(ql[ks], kh, s[f]);
            }
        // mask: lane holds rows g*4+j, col f*16+lr
#pragma unroll
        for (int f = 0; f < 2; ++f)
#pragma unroll
            for (int j = 0; j < 4; ++j) {
                int qrow = qt0 + g * 4 + j;
                int kcol = kv0 + f * 16 + lr;
                int mv = mbase[(size_t)qrow * T_ + kcol];
                if (!mv) s[f][j] = -1e30f;
            }
        // row max across the 16 lanes of this group
        float pm[4];
#pragma unroll
        for (int j = 0; j < 4; ++j) pm[j] = fmaxf(s[0][j], s[1][j]);
#pragma unroll
        for (int d = 1; d < 16; d <<= 1)
#pragma unroll
            for (int j = 0; j < 4; ++j) pm[j] = fmaxf(pm[j], __shfl_xor(pm[j], d));
        float fac[4];
#pragma unroll
        for (int j = 0; j < 4; ++j) {
            float mn = fmaxf(m_run[j], pm[j]);
            fac[j] = exp2f((m_run[j] - mn) * L2E);
            m_run[j] = mn;
        }
        float psum[4] = {0.f, 0.f, 0.f, 0.f};
        u16 pb[2][4];
#pragma unroll
        for (int f = 0; f < 2; ++f)
#pragma unroll
            for (int j = 0; j < 4; ++j) {
                float p = exp2f((s[f][j] - m_run[j]) * L2E);
                psum[j] += p;
                pb[f][j] = f2bf(p);
            }
#pragma unroll
        for (int d = 1; d < 16; d <<= 1)
#pragma unroll
            for (int j = 0; j < 4; ++j) psum[j] += __shfl_xor(psum[j], d);
#pragma unroll
        for (int j = 0; j < 4; ++j) l_run[j] = l_run[j] * fac[j] + psum[j];
#pragma unroll
        for (int fc = 0; fc < 4; ++fc)
#pragma unroll
            for (int j = 0; j < 4; ++j) o[fc][j] *= fac[j];

        // transpose P (D-layout rows) -> A-fragment layout via per-wave LDS
#pragma unroll
        for (int f = 0; f < 2; ++f)
#pragma unroll
            for (int j = 0; j < 4; ++j)
                p_lds[w][(g * 4 + j) * 32 + f * 16 + lr] = pb[f][j];
        asm volatile("s_waitcnt lgkmcnt(0)" ::: "memory");
        __builtin_amdgcn_sched_barrier(0);
        short8 ap = *(const short8*)&p_lds[w][lr * 32 + g * 8];

        // PV: B[kv][dh] = Vt[dh][kv] -> contiguous 16B loads
#pragma unroll
        for (int fc = 0; fc < 4; ++fc) {
            short8 bv = *(const short8*)&Vh[(size_t)(fc * 16 + lr) * T_ + kv0 + g * 8];
            o[fc] = mfma16(ap, bv, o[fc]);
        }
    }

    float inv[4];
#pragma unroll
    for (int j = 0; j < 4; ++j) inv[j] = 1.0f / l_run[j];
#pragma unroll
    for (int fc = 0; fc < 4; ++fc)
#pragma unroll
        for (int j = 0; j < 4; ++j) {
            int t = qt0 + g * 4 + j;
            comb[((size_t)(b * T_ + t)) * D_ + h * DH_ + fc * 16 + lr] =
                f2bf(o[fc][j] * inv[j]);
        }
}

// ---------------------------------------------------------------------------
// Kernel 3: output projection.  out = comb(bf16) @ Wo + bo, fp32 out.
// ---------------------------------------------------------------------------
__global__ __launch_bounds__(256) void oproj_kernel(
    const u16* __restrict__ A, const float* __restrict__ W,
    const float* __restrict__ bias, float* __restrict__ out)
{
    __shared__ u16 s_a[64 * 32];
    __shared__ u16 s_bh[64 * 32];   // transposed [n][k]

    const int m0 = blockIdx.y * 64, n0 = blockIdx.x * 64;
    const int tid  = threadIdx.x;
    const int w    = tid >> 6;
    const int lane = tid & 63;
    const int g    = lane >> 4;
    const int lr   = lane & 15;
    const int wr = (w >> 1) * 32, wc = (w & 1) * 32;
    const int ar = tid >> 2, ak = (tid & 3) * 8;
    const int br = tid >> 3, bn = (tid & 7) * 8;

    f32x4 acc[2][2] = {};

    for (int k0 = 0; k0 < D_; k0 += 32) {
        short8 av = *(const short8*)(A + (size_t)(m0 + ar) * D_ + k0 + ak);
        float4 b0 = *(const float4*)(W + (size_t)(k0 + br) * D_ + n0 + bn);
        float4 b1 = *(const float4*)(W + (size_t)(k0 + br) * D_ + n0 + bn + 4);
        float bw[8] = {b0.x, b0.y, b0.z, b0.w, b1.x, b1.y, b1.z, b1.w};

        __syncthreads();
        *(short8*)&s_a[ar * 32 + ak] = av;
#pragma unroll
        for (int i = 0; i < 8; ++i) s_bh[(bn + i) * 32 + br] = f2bf(bw[i]);
        __syncthreads();

        short8 a0[2], bb[2];
#pragma unroll
        for (int f = 0; f < 2; ++f) {
            a0[f] = *(const short8*)&s_a[(wr + f * 16 + lr) * 32 + g * 8];
            bb[f] = *(const short8*)&s_bh[(wc + f * 16 + lr) * 32 + g * 8];
        }
#pragma unroll
        for (int fm = 0; fm < 2; ++fm)
#pragma unroll
            for (int fn = 0; fn < 2; ++fn)
                acc[fm][fn] = mfma16(a0[fm], bb[fn], acc[fm][fn]);
    }

#pragma unroll
    for (int fm = 0; fm < 2; ++fm)
#pragma unroll
        for (int fn = 0; fn < 2; ++fn)
#pragma unroll
            for (int j = 0; j < 4; ++j) {
                int r = m0 + wr + fm * 16 + g * 4 + j;
                int c = n0 + wc + fn * 16 + lr;
                out[(size_t)r * D_ + c] = acc[fm][fn][j] + bias[c];
            }
}

// ---------------------------------------------------------------------------
extern "C" void kernel_launch(void* const* d_in, const int* in_sizes, int n_in,
                              void* d_out, int out_size, void* d_ws, size_t ws_size,
                              hipStream_t stream)
{
    const float* X    = (const float*)d_in[0];
    const int*   mask = (const int*)d_in[1];
    const float* Wq   = (const float*)d_in[2];
    const float* bq   = (const float*)d_in[3];
    const float* Wk   = (const float*)d_in[4];
    const float* bk   = (const float*)d_in[5];
    const float* Wv   = (const float*)d_in[6];
    const float* bv   = (const float*)d_in[7];
    const float* Wo   = (const float*)d_in[8];
    const float* bo   = (const float*)d_in[9];
    float* out = (float*)d_out;

    char* ws = (char*)d_ws;
    const size_t SEG = (size_t)B_ * H_ * T_ * DH_ * sizeof(u16);  // 8 MiB
    u16* Qhi  = (u16*)(ws + 0 * SEG);
    u16* Qlo  = (u16*)(ws + 1 * SEG);
    u16* Khi  = (u16*)(ws + 2 * SEG);
    u16* Klo  = (u16*)(ws + 3 * SEG);
    u16* Vt   = (u16*)(ws + 4 * SEG);
    u16* comb = (u16*)(ws + 5 * SEG);

    dim3 blk(256);
    qkv_proj_kernel<<<dim3(D_ / 64, (B_ * T_) / 64, 3), blk, 0, stream>>>(
        X, Wq, bq, Wk, bk, Wv, bv, Qhi, Qlo, Khi, Klo, Vt);
    attn_kernel<<<dim3(B_ * H_ * (T_ / 64)), blk, 0, stream>>>(
        Qhi, Qlo, Khi, Klo, Vt, mask, comb);
    oproj_kernel<<<dim3(D_ / 64, (B_ * T_) / 64), blk, 0, stream>>>(
        comb, Wo, bo, out);
}

// Round 2
// 491.259 us; speedup vs baseline: 1.3299x; 1.3299x over previous
//
#include <hip/hip_runtime.h>
#include <hip/hip_bf16.h>
#include <stdint.h>

typedef __attribute__((ext_vector_type(8))) short short8;
typedef __attribute__((ext_vector_type(4))) float f32x4;
typedef __attribute__((ext_vector_type(16))) float f32x16;
typedef unsigned short u16;

#define B_  2
#define T_  2048
#define D_  1024
#define H_  16
#define DH_ 64

__device__ __forceinline__ u16 f2bf(float x) {
    union { float f; uint32_t u; } v; v.f = x;
    uint32_t r = v.u + 0x7fffu + ((v.u >> 16) & 1u);
    return (u16)(r >> 16);
}
__device__ __forceinline__ float bf2f(u16 h) {
    union { uint32_t u; float f; } v; v.u = ((uint32_t)h) << 16;
    return v.f;
}
__device__ __forceinline__ f32x4 mfma16(short8 a, short8 b, f32x4 c) {
    return __builtin_amdgcn_mfma_f32_16x16x32_bf16(a, b, c, 0, 0, 0);
}
__device__ __forceinline__ f32x16 mfma32(short8 a, short8 b, f32x16 c) {
    return __builtin_amdgcn_mfma_f32_32x32x16_bf16(a, b, c, 0, 0, 0);
}

// ---------------------------------------------------------------------------
// Kernel 0: pack int32 mask -> bit mask.  1 MB total => L2-resident in attn.
// bits word k covers mask elements k*32 .. k*32+31 (bit j = element k*32+j).
// ---------------------------------------------------------------------------
__global__ __launch_bounds__(256) void maskpack_kernel(
    const int* __restrict__ mask, uint32_t* __restrict__ bits)
{
    size_t e = (size_t)blockIdx.x * 256 + threadIdx.x;
    unsigned long long b = __ballot(mask[e] != 0);
    if ((threadIdx.x & 63) == 0)
        *(unsigned long long*)(bits + (e >> 5)) = b;   // e is 64-aligned per wave
}

// ---------------------------------------------------------------------------
// Kernel 1: QKV projections (unchanged structure from R1; V skips lo-terms).
// ---------------------------------------------------------------------------
__global__ __launch_bounds__(256) void qkv_proj_kernel(
    const float* __restrict__ X,
    const float* __restrict__ Wq, const float* __restrict__ bq,
    const float* __restrict__ Wk, const float* __restrict__ bk,
    const float* __restrict__ Wv, const float* __restrict__ bv,
    u16* __restrict__ Qhi, u16* __restrict__ Qlo,
    u16* __restrict__ Khi, u16* __restrict__ Klo,
    u16* __restrict__ Vt)
{
    __shared__ u16 s_ahi[64 * 32];
    __shared__ u16 s_alo[64 * 32];
    __shared__ u16 s_bhi[64 * 32];   // transposed: [n][k]
    __shared__ u16 s_blo[64 * 32];

    const int z = blockIdx.z;
    const float* __restrict__ W   = (z == 0) ? Wq : (z == 1) ? Wk : Wv;
    const float* __restrict__ bia = (z == 0) ? bq : (z == 1) ? bk : bv;
    const float scale = (z == 0) ? 0.125f : 1.0f;   // dh^-0.5 = 1/8

    const int m0 = blockIdx.y * 64;
    const int n0 = blockIdx.x * 64;
    const int tid  = threadIdx.x;
    const int w    = tid >> 6;
    const int lane = tid & 63;
    const int g    = lane >> 4;
    const int lr   = lane & 15;
    const int wr = (w >> 1) * 32, wc = (w & 1) * 32;

    const int ar = tid >> 2, ak = (tid & 3) * 8;
    const int br = tid >> 3, bn = (tid & 7) * 8;

    f32x4 acc[2][2] = {};

    for (int k0 = 0; k0 < D_; k0 += 32) {
        float4 a0 = *(const float4*)(X + (size_t)(m0 + ar) * D_ + k0 + ak);
        float4 a1 = *(const float4*)(X + (size_t)(m0 + ar) * D_ + k0 + ak + 4);
        float4 b0 = *(const float4*)(W + (size_t)(k0 + br) * D_ + n0 + bn);
        float4 b1 = *(const float4*)(W + (size_t)(k0 + br) * D_ + n0 + bn + 4);
        float av[8] = {a0.x, a0.y, a0.z, a0.w, a1.x, a1.y, a1.z, a1.w};
        float bw[8] = {b0.x, b0.y, b0.z, b0.w, b1.x, b1.y, b1.z, b1.w};

        __syncthreads();
#pragma unroll
        for (int i = 0; i < 8; ++i) {
            u16 h = f2bf(av[i]);
            s_ahi[ar * 32 + ak + i] = h;
            s_alo[ar * 32 + ak + i] = f2bf(av[i] - bf2f(h));
        }
#pragma unroll
        for (int i = 0; i < 8; ++i) {
            u16 h = f2bf(bw[i]);
            s_bhi[(bn + i) * 32 + br] = h;
            s_blo[(bn + i) * 32 + br] = f2bf(bw[i] - bf2f(h));
        }
        __syncthreads();

        short8 ah[2], al[2], bh[2], bl[2];
#pragma unroll
        for (int f = 0; f < 2; ++f) {
            ah[f] = *(const short8*)&s_ahi[(wr + f * 16 + lr) * 32 + g * 8];
            al[f] = *(const short8*)&s_alo[(wr + f * 16 + lr) * 32 + g * 8];
            bh[f] = *(const short8*)&s_bhi[(wc + f * 16 + lr) * 32 + g * 8];
            bl[f] = *(const short8*)&s_blo[(wc + f * 16 + lr) * 32 + g * 8];
        }
#pragma unroll
        for (int fm = 0; fm < 2; ++fm)
#pragma unroll
            for (int fn = 0; fn < 2; ++fn) {
                acc[fm][fn] = mfma16(ah[fm], bh[fn], acc[fm][fn]);
                if (z != 2) {   // V is consumed as bf16 anyway; skip lo-terms
                    acc[fm][fn] = mfma16(ah[fm], bl[fn], acc[fm][fn]);
                    acc[fm][fn] = mfma16(al[fm], bh[fn], acc[fm][fn]);
                }
            }
    }

#pragma unroll
    for (int fm = 0; fm < 2; ++fm)
#pragma unroll
        for (int fn = 0; fn < 2; ++fn)
#pragma unroll
            for (int j = 0; j < 4; ++j) {
                int r = m0 + wr + fm * 16 + g * 4 + j;
                int c = n0 + wc + fn * 16 + lr;
                float v = (acc[fm][fn][j] + bia[c]) * scale;
                int b = r >> 11, t = r & (T_ - 1);
                int h = c >> 6,  d = c & 63;
                if (z == 2) {
                    Vt[((size_t)(b * H_ + h) * DH_ + d) * T_ + t] = f2bf(v);
                } else {
                    size_t idx = ((size_t)(b * H_ + h) * T_ + t) * DH_ + d;
                    u16 hv = f2bf(v);
                    u16 lv = f2bf(v - bf2f(hv));
                    if (z == 0) { Qhi[idx] = hv; Qlo[idx] = lv; }
                    else        { Khi[idx] = hv; Klo[idx] = lv; }
                }
            }
}

// ---------------------------------------------------------------------------
// Kernel 2: flash attention, swapped-QK^T 32x32x16 form.
// Wave = 32 q-rows.  Block = 4 waves = 128 q-rows.  Grid = B*H*(T/128) = 512.
// S = mfma(K,Q): D[kv=reg][q=lane&31] -> softmax stats lane-local.
// Mask via bit-packed words (1 load/lane/tile).  P -> PV B-frag in-register
// via v_cvt_pk_bf16_f32 + v_permlane32_swap_b32.  O = mfma(V,P): D[dh][q].
// Defer-max (THR=8).  No LDS at all.
// ---------------------------------------------------------------------------
__global__ __launch_bounds__(256) void attn2_kernel(
    const u16* __restrict__ Qhi, const u16* __restrict__ Qlo,
    const u16* __restrict__ Khi, const u16* __restrict__ Klo,
    const u16* __restrict__ Vt,  const uint32_t* __restrict__ bits,
    u16* __restrict__ comb)
{
    const int bx = blockIdx.x;
    const int qb = bx & 15;
    const int bh = bx >> 4;
    const int b  = bh >> 4, h = bh & 15;
    const int tid = threadIdx.x;
    const int w   = tid >> 6;
    const int l   = tid & 63;
    const int qi  = l & 31;          // q within wave strip (and D-col)
    const int hl  = l >> 5;          // half-wave
    const int q   = qb * 128 + w * 32 + qi;

    const size_t hoff = (size_t)(b * H_ + h) * T_ * DH_;
    const u16* Qh = Qhi + hoff;
    const u16* Ql = Qlo + hoff;
    const u16* Kh = Khi + hoff;
    const u16* Kl = Klo + hoff;
    const u16* Vh = Vt  + hoff;                        // [64][T]
    const uint32_t* mrow = bits + ((size_t)b * T_ + q) * (T_ / 32);

    // Q fragments: k-step c covers dh = c*16 + hl*8 + i
    short8 qfh[4], qfl[4];
#pragma unroll
    for (int c = 0; c < 4; ++c) {
        qfh[c] = *(const short8*)&Qh[(size_t)q * DH_ + c * 16 + hl * 8];
        qfl[c] = *(const short8*)&Ql[(size_t)q * DH_ + c * 16 + hl * 8];
    }

    f32x16 o0 = {}; f32x16 o1 = {};
    float m_run = -1e30f, l_run = 0.0f;
    const float L2E = 1.4426950408889634f;

    for (int kv0 = 0; kv0 < T_; kv0 += 32) {
        uint32_t mw = mrow[kv0 >> 5] >> (hl * 4);

        f32x16 s = {};
#pragma unroll
        for (int c = 0; c < 4; ++c) {
            short8 kh = *(const short8*)&Kh[(size_t)(kv0 + qi) * DH_ + c * 16 + hl * 8];
            short8 kl = *(const short8*)&Kl[(size_t)(kv0 + qi) * DH_ + c * 16 + hl * 8];
            s = mfma32(kh, qfh[c], s);   // hi*hi
            s = mfma32(kh, qfl[c], s);   // hi*lo
            s = mfma32(kl, qfh[c], s);   // lo*hi
        }

        // mask: reg r -> kv_local = (r&3) + 8*(r>>2) + 4*hl (mw pre-shifted)
#pragma unroll
        for (int r = 0; r < 16; ++r) {
            const int bit = (r & 3) + 8 * (r >> 2);
            if (!((mw >> bit) & 1u)) s[r] = -1e30f;
        }

        // row max: 15 in-lane + 1 cross-half shfl
        float pm = s[0];
#pragma unroll
        for (int r = 1; r < 16; ++r) pm = fmaxf(pm, s[r]);
        pm = fmaxf(pm, __shfl_xor(pm, 32));

        if (__any(pm > m_run + 8.0f)) {        // defer-max rescale (T13)
            float mn  = fmaxf(m_run, pm);
            float fac = exp2f((m_run - mn) * L2E);
            l_run *= fac;
#pragma unroll
            for (int r = 0; r < 16; ++r) { o0[r] *= fac; o1[r] *= fac; }
            m_run = mn;
        }

        float p[16]; float sum = 0.0f;
#pragma unroll
        for (int r = 0; r < 16; ++r) {
            p[r] = exp2f((s[r] - m_run) * L2E);
            sum += p[r];
        }
        sum += __shfl_xor(sum, 32);
        l_run += sum;

        // pack P to bf16 pairs; word m covers kv = 8*(m>>1) + 4*hl + 2*(m&1),+1
        uint32_t wv[8];
#pragma unroll
        for (int m2 = 0; m2 < 8; ++m2)
            asm("v_cvt_pk_bf16_f32 %0, %1, %2"
                : "=v"(wv[m2]) : "v"(p[2 * m2]), "v"(p[2 * m2 + 1]));
        // half-swap -> B-frag word order (kv = hl*8 + 2w,+1 per 16-kv group)
        asm("v_permlane32_swap_b32 %0, %1" : "+v"(wv[0]), "+v"(wv[2]));
        asm("v_permlane32_swap_b32 %0, %1" : "+v"(wv[1]), "+v"(wv[3]));
        asm("v_permlane32_swap_b32 %0, %1" : "+v"(wv[4]), "+v"(wv[6]));
        asm("v_permlane32_swap_b32 %0, %1" : "+v"(wv[5]), "+v"(wv[7]));
        union { uint32_t u[4]; short8 s8; } pa1, pa2;
        pa1.u[0] = wv[0]; pa1.u[1] = wv[1]; pa1.u[2] = wv[2]; pa1.u[3] = wv[3];
        pa2.u[0] = wv[4]; pa2.u[1] = wv[5]; pa2.u[2] = wv[6]; pa2.u[3] = wv[7];

        // PV: D[dh=reg][q=lane] ; A = Vt rows (dh), B = P
        short8 vb;
        vb = *(const short8*)&Vh[(size_t)(qi) * T_ + kv0 + hl * 8];
        o0 = mfma32(vb, pa1.s8, o0);
        vb = *(const short8*)&Vh[(size_t)(qi) * T_ + kv0 + 16 + hl * 8];
        o0 = mfma32(vb, pa2.s8, o0);
        vb = *(const short8*)&Vh[(size_t)(32 + qi) * T_ + kv0 + hl * 8];
        o1 = mfma32(vb, pa1.s8, o1);
        vb = *(const short8*)&Vh[(size_t)(32 + qi) * T_ + kv0 + 16 + hl * 8];
        o1 = mfma32(vb, pa2.s8, o1);
    }

    // epilogue: o_dt[r] = O[q][dh = dt*32 + 8*(r>>2) + 4*hl + (r&3)]
    float inv = 1.0f / l_run;
    float ov[32];
#pragma unroll
    for (int r = 0; r < 16; ++r) { ov[r] = o0[r]; ov[16 + r] = o1[r]; }
    u16* crow = comb + (size_t)(b * T_ + q) * D_ + h * DH_;
#pragma unroll
    for (int dt = 0; dt < 2; ++dt)
#pragma unroll
        for (int g2 = 0; g2 < 4; ++g2) {
            float v0 = ov[dt * 16 + 4 * g2 + 0] * inv;
            float v1 = ov[dt * 16 + 4 * g2 + 1] * inv;
            float v2 = ov[dt * 16 + 4 * g2 + 2] * inv;
            float v3 = ov[dt * 16 + 4 * g2 + 3] * inv;
            uint2 pkt;
            pkt.x = (uint32_t)f2bf(v0) | ((uint32_t)f2bf(v1) << 16);
            pkt.y = (uint32_t)f2bf(v2) | ((uint32_t)f2bf(v3) << 16);
            *(uint2*)(crow + dt * 32 + 8 * g2 + 4 * hl) = pkt;
        }
}

// ---------------------------------------------------------------------------
// Kernel 3: output projection (unchanged from R1).
// ---------------------------------------------------------------------------
__global__ __launch_bounds__(256) void oproj_kernel(
    const u16* __restrict__ A, const float* __restrict__ W,
    const float* __restrict__ bias, float* __restrict__ out)
{
    __shared__ u16 s_a[64 * 32];
    __shared__ u16 s_bh[64 * 32];

    const int m0 = blockIdx.y * 64, n0 = blockIdx.x * 64;
    const int tid  = threadIdx.x;
    const int w    = tid >> 6;
    const int lane = tid & 63;
    const int g    = lane >> 4;
    const int lr   = lane & 15;
    const int wr = (w >> 1) * 32, wc = (w & 1) * 32;
    const int ar = tid >> 2, ak = (tid & 3) * 8;
    const int br = tid >> 3, bn = (tid & 7) * 8;

    f32x4 acc[2][2] = {};

    for (int k0 = 0; k0 < D_; k0 += 32) {
        short8 av = *(const short8*)(A + (size_t)(m0 + ar) * D_ + k0 + ak);
        float4 b0 = *(const float4*)(W + (size_t)(k0 + br) * D_ + n0 + bn);
        float4 b1 = *(const float4*)(W + (size_t)(k0 + br) * D_ + n0 + bn + 4);
        float bw[8] = {b0.x, b0.y, b0.z, b0.w, b1.x, b1.y, b1.z, b1.w};

        __syncthreads();
        *(short8*)&s_a[ar * 32 + ak] = av;
#pragma unroll
        for (int i = 0; i < 8; ++i) s_bh[(bn + i) * 32 + br] = f2bf(bw[i]);
        __syncthreads();

        short8 a0[2], bb[2];
#pragma unroll
        for (int f = 0; f < 2; ++f) {
            a0[f] = *(const short8*)&s_a[(wr + f * 16 + lr) * 32 + g * 8];
            bb[f] = *(const short8*)&s_bh[(wc + f * 16 + lr) * 32 + g * 8];
        }
#pragma unroll
        for (int fm = 0; fm < 2; ++fm)
#pragma unroll
            for (int fn = 0; fn < 2; ++fn)
                acc[fm][fn] = mfma16(a0[fm], bb[fn], acc[fm][fn]);
    }

#pragma unroll
    for (int fm = 0; fm < 2; ++fm)
#pragma unroll
        for (int fn = 0; fn < 2; ++fn)
#pragma unroll
            for (int j = 0; j < 4; ++j) {
                int r = m0 + wr + fm * 16 + g * 4 + j;
                int c = n0 + wc + fn * 16 + lr;
                out[(size_t)r * D_ + c] = acc[fm][fn][j] + bias[c];
            }
}

// ---------------------------------------------------------------------------
extern "C" void kernel_launch(void* const* d_in, const int* in_sizes, int n_in,
                              void* d_out, int out_size, void* d_ws, size_t ws_size,
                              hipStream_t stream)
{
    const float* X    = (const float*)d_in[0];
    const int*   mask = (const int*)d_in[1];
    const float* Wq   = (const float*)d_in[2];
    const float* bq   = (const float*)d_in[3];
    const float* Wk   = (const float*)d_in[4];
    const float* bk   = (const float*)d_in[5];
    const float* Wv   = (const float*)d_in[6];
    const float* bv   = (const float*)d_in[7];
    const float* Wo   = (const float*)d_in[8];
    const float* bo   = (const float*)d_in[9];
    float* out = (float*)d_out;

    char* ws = (char*)d_ws;
    const size_t SEG = (size_t)B_ * H_ * T_ * DH_ * sizeof(u16);  // 8 MiB
    u16* Qhi  = (u16*)(ws + 0 * SEG);
    u16* Qlo  = (u16*)(ws + 1 * SEG);
    u16* Khi  = (u16*)(ws + 2 * SEG);
    u16* Klo  = (u16*)(ws + 3 * SEG);
    u16* Vt   = (u16*)(ws + 4 * SEG);
    u16* comb = (u16*)(ws + 5 * SEG);
    // mask bits (1 MiB) live in d_out scratch space (bytes 8..9 MiB of the
    // 16 MiB output buffer); oproj overwrites all of d_out afterwards.
    uint32_t* bits = (uint32_t*)((char*)d_out + (8u << 20));

    dim3 blk(256);
    maskpack_kernel<<<dim3((B_ * T_ * T_) / 256), blk, 0, stream>>>(mask, bits);
    qkv_proj_kernel<<<dim3(D_ / 64, (B_ * T_) / 64, 3), blk, 0, stream>>>(
        X, Wq, bq, Wk, bk, Wv, bv, Qhi, Qlo, Khi, Klo, Vt);
    attn2_kernel<<<dim3(B_ * H_ * (T_ / 128)), blk, 0, stream>>>(
        Qhi, Qlo, Khi, Klo, Vt, bits, comb);
    oproj_kernel<<<dim3(D_ / 64, (B_ * T_) / 64), blk, 0, stream>>>(
        comb, Wo, bo, out);
}

// Round 3
// 313.777 us; speedup vs baseline: 2.0821x; 1.5656x over previous
//
#include <hip/hip_runtime.h>
#include <hip/hip_bf16.h>
#include <stdint.h>

typedef __attribute__((ext_vector_type(8))) short short8;
typedef __attribute__((ext_vector_type(4))) float f32x4;
typedef __attribute__((ext_vector_type(16))) float f32x16;
typedef unsigned short u16;

#define B_  2
#define T_  2048
#define D_  1024
#define H_  16
#define DH_ 64

__device__ __forceinline__ u16 f2bf(float x) {
    union { float f; uint32_t u; } v; v.f = x;
    uint32_t r = v.u + 0x7fffu + ((v.u >> 16) & 1u);
    return (u16)(r >> 16);
}
__device__ __forceinline__ float bf2f(u16 h) {
    union { uint32_t u; float f; } v; v.u = ((uint32_t)h) << 16;
    return v.f;
}
__device__ __forceinline__ f32x4 mfma16(short8 a, short8 b, f32x4 c) {
    return __builtin_amdgcn_mfma_f32_16x16x32_bf16(a, b, c, 0, 0, 0);
}
__device__ __forceinline__ f32x16 mfma32(short8 a, short8 b, f32x16 c) {
    return __builtin_amdgcn_mfma_f32_32x32x16_bf16(a, b, c, 0, 0, 0);
}
// async global->LDS, 16B per lane; LDS dest = wave-uniform base + lane*16
__device__ __forceinline__ void gload16(const u16* g, u16* l) {
    __builtin_amdgcn_global_load_lds(
        (const __attribute__((address_space(1))) uint32_t*)g,
        (__attribute__((address_space(3))) uint32_t*)l, 16, 0, 0);
}

// ---------------------------------------------------------------------------
// Kernel 0: pack int32 mask -> bit mask (1 MB, L2-resident in attn).
// ---------------------------------------------------------------------------
__global__ __launch_bounds__(256) void maskpack_kernel(
    const int* __restrict__ mask, uint32_t* __restrict__ bits)
{
    size_t e = (size_t)blockIdx.x * 256 + threadIdx.x;
    unsigned long long b = __ballot(mask[e] != 0);
    if ((threadIdx.x & 63) == 0)
        *(unsigned long long*)(bits + (e >> 5)) = b;
}

// ---------------------------------------------------------------------------
// Kernel 0b: split X fp32 -> Xhi/Xlo bf16 (one-time conversion).
// ---------------------------------------------------------------------------
__global__ __launch_bounds__(256) void splitx_kernel(
    const float* __restrict__ X, u16* __restrict__ Xhi, u16* __restrict__ Xlo)
{
    size_t i0 = ((size_t)blockIdx.x * 256 + threadIdx.x) * 8;
    float4 a = *(const float4*)(X + i0);
    float4 b = *(const float4*)(X + i0 + 4);
    float v[8] = {a.x, a.y, a.z, a.w, b.x, b.y, b.z, b.w};
    union { u16 h[8]; short8 s; } Hh, Ll;
#pragma unroll
    for (int i = 0; i < 8; ++i) {
        Hh.h[i] = f2bf(v[i]);
        Ll.h[i] = f2bf(v[i] - bf2f(Hh.h[i]));
    }
    *(short8*)(Xhi + i0) = Hh.s;
    *(short8*)(Xlo + i0) = Ll.s;
}

// ---------------------------------------------------------------------------
// Kernel 0c: transpose + split weights.  W[k][n] fp32 -> WT[n][k] bf16.
// z: 0=Wq(hi+lo) 1=Wk(hi+lo) 2=Wv(hi) 3=Wo(hi).
// ---------------------------------------------------------------------------
__global__ __launch_bounds__(256) void wtr_kernel(
    const float* __restrict__ Wq, const float* __restrict__ Wk,
    const float* __restrict__ Wv, const float* __restrict__ Wo,
    u16* __restrict__ WqThi, u16* __restrict__ WqTlo,
    u16* __restrict__ WkThi, u16* __restrict__ WkTlo,
    u16* __restrict__ WvT,   u16* __restrict__ WoT)
{
    __shared__ float s_t[64][65];
    const int zz = blockIdx.z;
    const float* __restrict__ W = (zz == 0) ? Wq : (zz == 1) ? Wk : (zz == 2) ? Wv : Wo;
    const int k0 = blockIdx.y * 64, n0 = blockIdx.x * 64;
    const int t = threadIdx.x;
    const int r = t >> 2, c0 = (t & 3) * 16;

#pragma unroll
    for (int j = 0; j < 4; ++j) {
        float4 v = *(const float4*)(W + (size_t)(k0 + r) * D_ + n0 + c0 + j * 4);
        s_t[r][c0 + j * 4 + 0] = v.x;
        s_t[r][c0 + j * 4 + 1] = v.y;
        s_t[r][c0 + j * 4 + 2] = v.z;
        s_t[r][c0 + j * 4 + 3] = v.w;
    }
    __syncthreads();

    const int n = t >> 2, kc = (t & 3) * 16;
    union { u16 h[16]; short8 s[2]; } Hh, Ll;
#pragma unroll
    for (int j = 0; j < 16; ++j) {
        float x = s_t[kc + j][n];
        Hh.h[j] = f2bf(x);
        Ll.h[j] = f2bf(x - bf2f(Hh.h[j]));
    }
    u16* dh = (zz == 0) ? WqThi : (zz == 1) ? WkThi : (zz == 2) ? WvT : WoT;
    u16* dl = (zz == 0) ? WqTlo : (zz == 1) ? WkTlo : nullptr;
    size_t o = (size_t)(n0 + n) * D_ + k0 + kc;
    *(short8*)(dh + o) = Hh.s[0];
    *(short8*)(dh + o + 8) = Hh.s[1];
    if (dl) {
        *(short8*)(dl + o) = Ll.s[0];
        *(short8*)(dl + o + 8) = Ll.s[1];
    }
}

// ---------------------------------------------------------------------------
// Kernel 1: m97-style 128x128 GEMM, BK=32, global_load_lds staging.
// z = blockIdx.z + zbase:  0=Q (split out, *1/8)  1=K (split out)
//                          2=V (bf16, transposed [B,H,64,T])  3=O (fp32+bias)
// Q/K use 3-term split-bf16 (A=Xhi/Xlo, B=WT hi/lo); V/O plain bf16.
// ---------------------------------------------------------------------------
__global__ __launch_bounds__(256) void gemm_kernel(
    const u16* __restrict__ Ahi, const u16* __restrict__ Alo, int zbase,
    const u16* __restrict__ BqH, const u16* __restrict__ BqL,
    const u16* __restrict__ BkH, const u16* __restrict__ BkL,
    const u16* __restrict__ BvT, const u16* __restrict__ BoT,
    const float* __restrict__ bq, const float* __restrict__ bk,
    const float* __restrict__ bv, const float* __restrict__ bo,
    u16* __restrict__ Qhi, u16* __restrict__ Qlo,
    u16* __restrict__ Khi, u16* __restrict__ Klo,
    u16* __restrict__ Vt,  float* __restrict__ outF)
{
    __shared__ u16 sAhi[128 * 32];
    __shared__ u16 sAlo[128 * 32];
    __shared__ u16 sBhi[128 * 32];
    __shared__ u16 sBlo[128 * 32];

    const int z = blockIdx.z + zbase;
    const u16* __restrict__ Bh = (z == 0) ? BqH : (z == 1) ? BkH : (z == 2) ? BvT : BoT;
    const u16* __restrict__ Bl = (z == 0) ? BqL : (z == 1) ? BkL : nullptr;
    const float* __restrict__ bias = (z == 0) ? bq : (z == 1) ? bk : (z == 2) ? bv : bo;
    const bool split = (z < 2);

    const int m0 = blockIdx.y * 128;
    const int n0 = blockIdx.x * 128;
    const int tid = threadIdx.x;
    const int w = tid >> 6, l = tid & 63;
    const int g = l >> 4, lr = l & 15;
    const int wm = w >> 1, wn = w & 1;

    // staging map: wave w covers rows w*32..w*32+31 (2 calls x 16 rows)
    const int srow = w * 32 + (l >> 2);
    const int skb  = (l & 3) * 8;

    f32x4 acc[4][4] = {};

    for (int k0 = 0; k0 < D_; k0 += 32) {
        __syncthreads();   // previous iteration's LDS reads complete
#pragma unroll
        for (int i = 0; i < 2; ++i) {
            gload16(Ahi + (size_t)(m0 + srow + i * 16) * D_ + k0 + skb,
                    &sAhi[w * 1024 + i * 512]);
            gload16(Bh + (size_t)(n0 + srow + i * 16) * D_ + k0 + skb,
                    &sBhi[w * 1024 + i * 512]);
        }
        if (split) {
#pragma unroll
            for (int i = 0; i < 2; ++i) {
                gload16(Alo + (size_t)(m0 + srow + i * 16) * D_ + k0 + skb,
                        &sAlo[w * 1024 + i * 512]);
                gload16(Bl + (size_t)(n0 + srow + i * 16) * D_ + k0 + skb,
                        &sBlo[w * 1024 + i * 512]);
            }
        }
        __syncthreads();   // drains vmcnt -> staged data visible

        short8 ah[4], bh[4];
#pragma unroll
        for (int f = 0; f < 4; ++f) {
            ah[f] = *(const short8*)&sAhi[(wm * 64 + f * 16 + lr) * 32 + g * 8];
            bh[f] = *(const short8*)&sBhi[(wn * 64 + f * 16 + lr) * 32 + g * 8];
        }
#pragma unroll
        for (int fm = 0; fm < 4; ++fm)
#pragma unroll
            for (int fn = 0; fn < 4; ++fn)
                acc[fm][fn] = mfma16(ah[fm], bh[fn], acc[fm][fn]);
        if (split) {
            short8 al[4], bl[4];
#pragma unroll
            for (int f = 0; f < 4; ++f) {
                al[f] = *(const short8*)&sAlo[(wm * 64 + f * 16 + lr) * 32 + g * 8];
                bl[f] = *(const short8*)&sBlo[(wn * 64 + f * 16 + lr) * 32 + g * 8];
            }
#pragma unroll
            for (int fm = 0; fm < 4; ++fm)
#pragma unroll
                for (int fn = 0; fn < 4; ++fn) {
                    acc[fm][fn] = mfma16(ah[fm], bl[fn], acc[fm][fn]);
                    acc[fm][fn] = mfma16(al[fm], bh[fn], acc[fm][fn]);
                }
        }
    }

    const float scale = (z == 0) ? 0.125f : 1.0f;
    float biasv[4];
#pragma unroll
    for (int f = 0; f < 4; ++f) biasv[f] = bias[n0 + wn * 64 + f * 16 + lr];

    if (z <= 1) {
        u16* Oh = (z == 0) ? Qhi : Khi;
        u16* Ol = (z == 0) ? Qlo : Klo;
#pragma unroll
        for (int fm = 0; fm < 4; ++fm)
#pragma unroll
            for (int fn = 0; fn < 4; ++fn)
#pragma unroll
                for (int j = 0; j < 4; ++j) {
                    int r = m0 + wm * 64 + fm * 16 + g * 4 + j;
                    int c = n0 + wn * 64 + fn * 16 + lr;
                    float v = (acc[fm][fn][j] + biasv[fn]) * scale;
                    int b = r >> 11, t = r & (T_ - 1);
                    int h = (c >> 6) & 15, d = c & 63;
                    size_t idx = ((size_t)(b * H_ + h) * T_ + t) * DH_ + d;
                    u16 hv = f2bf(v);
                    Oh[idx] = hv;
                    Ol[idx] = f2bf(v - bf2f(hv));
                }
    } else if (z == 2) {
#pragma unroll
        for (int fm = 0; fm < 4; ++fm)
#pragma unroll
            for (int fn = 0; fn < 4; ++fn) {
                int r0 = m0 + wm * 64 + fm * 16 + g * 4;
                int c  = n0 + wn * 64 + fn * 16 + lr;
                int b = r0 >> 11, t0 = r0 & (T_ - 1);
                int h = (c >> 6) & 15, d = c & 63;
                uint2 pk;
                pk.x = (uint32_t)f2bf(acc[fm][fn][0] + biasv[fn]) |
                       ((uint32_t)f2bf(acc[fm][fn][1] + biasv[fn]) << 16);
                pk.y = (uint32_t)f2bf(acc[fm][fn][2] + biasv[fn]) |
                       ((uint32_t)f2bf(acc[fm][fn][3] + biasv[fn]) << 16);
                *(uint2*)&Vt[((size_t)(b * H_ + h) * DH_ + d) * T_ + t0] = pk;
            }
    } else {
#pragma unroll
        for (int fm = 0; fm < 4; ++fm)
#pragma unroll
            for (int fn = 0; fn < 4; ++fn)
#pragma unroll
                for (int j = 0; j < 4; ++j) {
                    int r = m0 + wm * 64 + fm * 16 + g * 4 + j;
                    int c = n0 + wn * 64 + fn * 16 + lr;
                    outF[(size_t)r * D_ + c] = acc[fm][fn][j] + biasv[fn];
                }
    }
}

// ---------------------------------------------------------------------------
// Kernel 2: flash attention, swapped-QK^T 32x32x16 (unchanged from R2,
// plus s_setprio around MFMA clusters).
// ---------------------------------------------------------------------------
__global__ __launch_bounds__(256) void attn2_kernel(
    const u16* __restrict__ Qhi, const u16* __restrict__ Qlo,
    const u16* __restrict__ Khi, const u16* __restrict__ Klo,
    const u16* __restrict__ Vt,  const uint32_t* __restrict__ bits,
    u16* __restrict__ comb)
{
    const int bx = blockIdx.x;
    const int qb = bx & 15;
    const int bh = bx >> 4;
    const int b  = bh >> 4, h = bh & 15;
    const int tid = threadIdx.x;
    const int w   = tid >> 6;
    const int l   = tid & 63;
    const int qi  = l & 31;
    const int hl  = l >> 5;
    const int q   = qb * 128 + w * 32 + qi;

    const size_t hoff = (size_t)(b * H_ + h) * T_ * DH_;
    const u16* Qh = Qhi + hoff;
    const u16* Ql = Qlo + hoff;
    const u16* Kh = Khi + hoff;
    const u16* Kl = Klo + hoff;
    const u16* Vh = Vt  + hoff;                        // [64][T]
    const uint32_t* mrow = bits + ((size_t)b * T_ + q) * (T_ / 32);

    short8 qfh[4], qfl[4];
#pragma unroll
    for (int c = 0; c < 4; ++c) {
        qfh[c] = *(const short8*)&Qh[(size_t)q * DH_ + c * 16 + hl * 8];
        qfl[c] = *(const short8*)&Ql[(size_t)q * DH_ + c * 16 + hl * 8];
    }

    f32x16 o0 = {}; f32x16 o1 = {};
    float m_run = -1e30f, l_run = 0.0f;
    const float L2E = 1.4426950408889634f;

    for (int kv0 = 0; kv0 < T_; kv0 += 32) {
        uint32_t mw = mrow[kv0 >> 5] >> (hl * 4);

        f32x16 s = {};
        __builtin_amdgcn_s_setprio(1);
#pragma unroll
        for (int c = 0; c < 4; ++c) {
            short8 kh = *(const short8*)&Kh[(size_t)(kv0 + qi) * DH_ + c * 16 + hl * 8];
            short8 kl = *(const short8*)&Kl[(size_t)(kv0 + qi) * DH_ + c * 16 + hl * 8];
            s = mfma32(kh, qfh[c], s);
            s = mfma32(kh, qfl[c], s);
            s = mfma32(kl, qfh[c], s);
        }
        __builtin_amdgcn_s_setprio(0);

#pragma unroll
        for (int r = 0; r < 16; ++r) {
            const int bit = (r & 3) + 8 * (r >> 2);
            if (!((mw >> bit) & 1u)) s[r] = -1e30f;
        }

        float pm = s[0];
#pragma unroll
        for (int r = 1; r < 16; ++r) pm = fmaxf(pm, s[r]);
        pm = fmaxf(pm, __shfl_xor(pm, 32));

        if (__any(pm > m_run + 8.0f)) {
            float mn  = fmaxf(m_run, pm);
            float fac = exp2f((m_run - mn) * L2E);
            l_run *= fac;
#pragma unroll
            for (int r = 0; r < 16; ++r) { o0[r] *= fac; o1[r] *= fac; }
            m_run = mn;
        }

        float p[16]; float sum = 0.0f;
#pragma unroll
        for (int r = 0; r < 16; ++r) {
            p[r] = exp2f((s[r] - m_run) * L2E);
            sum += p[r];
        }
        sum += __shfl_xor(sum, 32);
        l_run += sum;

        uint32_t wv[8];
#pragma unroll
        for (int m2 = 0; m2 < 8; ++m2)
            asm("v_cvt_pk_bf16_f32 %0, %1, %2"
                : "=v"(wv[m2]) : "v"(p[2 * m2]), "v"(p[2 * m2 + 1]));
        asm("v_permlane32_swap_b32 %0, %1" : "+v"(wv[0]), "+v"(wv[2]));
        asm("v_permlane32_swap_b32 %0, %1" : "+v"(wv[1]), "+v"(wv[3]));
        asm("v_permlane32_swap_b32 %0, %1" : "+v"(wv[4]), "+v"(wv[6]));
        asm("v_permlane32_swap_b32 %0, %1" : "+v"(wv[5]), "+v"(wv[7]));
        union { uint32_t u[4]; short8 s8; } pa1, pa2;
        pa1.u[0] = wv[0]; pa1.u[1] = wv[1]; pa1.u[2] = wv[2]; pa1.u[3] = wv[3];
        pa2.u[0] = wv[4]; pa2.u[1] = wv[5]; pa2.u[2] = wv[6]; pa2.u[3] = wv[7];

        __builtin_amdgcn_s_setprio(1);
        short8 vb;
        vb = *(const short8*)&Vh[(size_t)(qi) * T_ + kv0 + hl * 8];
        o0 = mfma32(vb, pa1.s8, o0);
        vb = *(const short8*)&Vh[(size_t)(qi) * T_ + kv0 + 16 + hl * 8];
        o0 = mfma32(vb, pa2.s8, o0);
        vb = *(const short8*)&Vh[(size_t)(32 + qi) * T_ + kv0 + hl * 8];
        o1 = mfma32(vb, pa1.s8, o1);
        vb = *(const short8*)&Vh[(size_t)(32 + qi) * T_ + kv0 + 16 + hl * 8];
        o1 = mfma32(vb, pa2.s8, o1);
        __builtin_amdgcn_s_setprio(0);
    }

    float inv = 1.0f / l_run;
    float ov[32];
#pragma unroll
    for (int r = 0; r < 16; ++r) { ov[r] = o0[r]; ov[16 + r] = o1[r]; }
    u16* crow = comb + (size_t)(b * T_ + q) * D_ + h * DH_;
#pragma unroll
    for (int dt = 0; dt < 2; ++dt)
#pragma unroll
        for (int g2 = 0; g2 < 4; ++g2) {
            float v0 = ov[dt * 16 + 4 * g2 + 0] * inv;
            float v1 = ov[dt * 16 + 4 * g2 + 1] * inv;
            float v2 = ov[dt * 16 + 4 * g2 + 2] * inv;
            float v3 = ov[dt * 16 + 4 * g2 + 3] * inv;
            uint2 pkt;
            pkt.x = (uint32_t)f2bf(v0) | ((uint32_t)f2bf(v1) << 16);
            pkt.y = (uint32_t)f2bf(v2) | ((uint32_t)f2bf(v3) << 16);
            *(uint2*)(crow + dt * 32 + 8 * g2 + 4 * hl) = pkt;
        }
}

// ---------------------------------------------------------------------------
extern "C" void kernel_launch(void* const* d_in, const int* in_sizes, int n_in,
                              void* d_out, int out_size, void* d_ws, size_t ws_size,
                              hipStream_t stream)
{
    const float* X    = (const float*)d_in[0];
    const int*   mask = (const int*)d_in[1];
    const float* Wq   = (const float*)d_in[2];
    const float* bq   = (const float*)d_in[3];
    const float* Wk   = (const float*)d_in[4];
    const float* bk   = (const float*)d_in[5];
    const float* Wv   = (const float*)d_in[6];
    const float* bv   = (const float*)d_in[7];
    const float* Wo   = (const float*)d_in[8];
    const float* bo   = (const float*)d_in[9];
    float* out = (float*)d_out;

    // workspace layout (u16 elements; SEG = 4,194,304 elems = 8 MiB)
    const size_t SEG = (size_t)B_ * H_ * T_ * DH_;   // = B*T*D
    const size_t WSEG = (size_t)D_ * D_;             // 1,048,576 elems = 2 MiB
    u16* wsp = (u16*)d_ws;
    u16* Qhi   = wsp + 0 * SEG;
    u16* Qlo   = wsp + 1 * SEG;
    u16* Khi   = wsp + 2 * SEG;
    u16* Klo   = wsp + 3 * SEG;
    u16* Xhi   = wsp + 4 * SEG;        // aliased: comb (attn output) after GEMMs
    u16* Xlo   = wsp + 5 * SEG;
    u16* WqThi = wsp + 6 * SEG;
    u16* WqTlo = WqThi + WSEG;
    u16* WkThi = WqThi + 2 * WSEG;
    u16* WkTlo = WqThi + 3 * WSEG;
    u16* WvT   = WqThi + 4 * WSEG;
    u16* WoT   = WqThi + 5 * WSEG;     // ws total: 60 MiB
    u16* comb  = Xhi;
    // d_out scratch: Vt (8 MiB) + mask bits (1 MiB); overwritten by final GEMM
    u16* Vt = (u16*)d_out;
    uint32_t* bits = (uint32_t*)((char*)d_out + (8u << 20));

    dim3 blk(256);
    maskpack_kernel<<<dim3((B_ * T_ * T_) / 256), blk, 0, stream>>>(mask, bits);
    splitx_kernel<<<dim3((B_ * T_ * D_) / 2048), blk, 0, stream>>>(X, Xhi, Xlo);
    wtr_kernel<<<dim3(16, 16, 4), blk, 0, stream>>>(
        Wq, Wk, Wv, Wo, WqThi, WqTlo, WkThi, WkTlo, WvT, WoT);
    gemm_kernel<<<dim3(D_ / 128, (B_ * T_) / 128, 3), blk, 0, stream>>>(
        Xhi, Xlo, 0, WqThi, WqTlo, WkThi, WkTlo, WvT, WoT,
        bq, bk, bv, bo, Qhi, Qlo, Khi, Klo, Vt, out);
    attn2_kernel<<<dim3(B_ * H_ * (T_ / 128)), blk, 0, stream>>>(
        Qhi, Qlo, Khi, Klo, Vt, bits, comb);
    gemm_kernel<<<dim3(D_ / 128, (B_ * T_) / 128, 1), blk, 0, stream>>>(
        comb, nullptr, 3, WqThi, WqTlo, WkThi, WkTlo, WvT, WoT,
        bq, bk, bv, bo, Qhi, Qlo, Khi, Klo, Vt, out);
}

// Round 4
// 297.614 us; speedup vs baseline: 2.1952x; 1.0543x over previous
//
#include <hip/hip_runtime.h>
#include <hip/hip_bf16.h>
#include <stdint.h>

typedef __attribute__((ext_vector_type(8))) short short8;
typedef __attribute__((ext_vector_type(4))) float f32x4;
typedef __attribute__((ext_vector_type(16))) float f32x16;
typedef unsigned short u16;

#define B_  2
#define T_  2048
#define D_  1024
#define H_  16
#define DH_ 64

__device__ __forceinline__ u16 f2bf(float x) {
    union { float f; uint32_t u; } v; v.f = x;
    uint32_t r = v.u + 0x7fffu + ((v.u >> 16) & 1u);
    return (u16)(r >> 16);
}
__device__ __forceinline__ float bf2f(u16 h) {
    union { uint32_t u; float f; } v; v.u = ((uint32_t)h) << 16;
    return v.f;
}
__device__ __forceinline__ f32x4 mfma16(short8 a, short8 b, f32x4 c) {
    return __builtin_amdgcn_mfma_f32_16x16x32_bf16(a, b, c, 0, 0, 0);
}
__device__ __forceinline__ f32x16 mfma32(short8 a, short8 b, f32x16 c) {
    return __builtin_amdgcn_mfma_f32_32x32x16_bf16(a, b, c, 0, 0, 0);
}
// async global->LDS, 16B per lane; LDS dest = wave-uniform base + lane*16
__device__ __forceinline__ void gload16(const u16* g, u16* l) {
    __builtin_amdgcn_global_load_lds(
        (const __attribute__((address_space(1))) uint32_t*)g,
        (__attribute__((address_space(3))) uint32_t*)l, 16, 0, 0);
}

// ---------------------------------------------------------------------------
// Kernel 0: pack int32 mask -> bit mask (1 MB, L2-resident in attn).
// ---------------------------------------------------------------------------
__global__ __launch_bounds__(256) void maskpack_kernel(
    const int* __restrict__ mask, uint32_t* __restrict__ bits)
{
    size_t e = (size_t)blockIdx.x * 256 + threadIdx.x;
    unsigned long long b = __ballot(mask[e] != 0);
    if ((threadIdx.x & 63) == 0)
        *(unsigned long long*)(bits + (e >> 5)) = b;
}

// ---------------------------------------------------------------------------
// Kernel 0b: split X fp32 -> Xhi/Xlo bf16 (one-time conversion).
// ---------------------------------------------------------------------------
__global__ __launch_bounds__(256) void splitx_kernel(
    const float* __restrict__ X, u16* __restrict__ Xhi, u16* __restrict__ Xlo)
{
    size_t i0 = ((size_t)blockIdx.x * 256 + threadIdx.x) * 8;
    float4 a = *(const float4*)(X + i0);
    float4 b = *(const float4*)(X + i0 + 4);
    float v[8] = {a.x, a.y, a.z, a.w, b.x, b.y, b.z, b.w};
    union { u16 h[8]; short8 s; } Hh, Ll;
#pragma unroll
    for (int i = 0; i < 8; ++i) {
        Hh.h[i] = f2bf(v[i]);
        Ll.h[i] = f2bf(v[i] - bf2f(Hh.h[i]));
    }
    *(short8*)(Xhi + i0) = Hh.s;
    *(short8*)(Xlo + i0) = Ll.s;
}

// ---------------------------------------------------------------------------
// Kernel 0c: transpose + split weights.  W[k][n] fp32 -> WT[n][k] bf16.
// z: 0=Wq(hi+lo) 1=Wk(hi+lo) 2=Wv(hi) 3=Wo(hi).
// ---------------------------------------------------------------------------
__global__ __launch_bounds__(256) void wtr_kernel(
    const float* __restrict__ Wq, const float* __restrict__ Wk,
    const float* __restrict__ Wv, const float* __restrict__ Wo,
    u16* __restrict__ WqThi, u16* __restrict__ WqTlo,
    u16* __restrict__ WkThi, u16* __restrict__ WkTlo,
    u16* __restrict__ WvT,   u16* __restrict__ WoT)
{
    __shared__ float s_t[64][65];
    const int zz = blockIdx.z;
    const float* __restrict__ W = (zz == 0) ? Wq : (zz == 1) ? Wk : (zz == 2) ? Wv : Wo;
    const int k0 = blockIdx.y * 64, n0 = blockIdx.x * 64;
    const int t = threadIdx.x;
    const int r = t >> 2, c0 = (t & 3) * 16;

#pragma unroll
    for (int j = 0; j < 4; ++j) {
        float4 v = *(const float4*)(W + (size_t)(k0 + r) * D_ + n0 + c0 + j * 4);
        s_t[r][c0 + j * 4 + 0] = v.x;
        s_t[r][c0 + j * 4 + 1] = v.y;
        s_t[r][c0 + j * 4 + 2] = v.z;
        s_t[r][c0 + j * 4 + 3] = v.w;
    }
    __syncthreads();

    const int n = t >> 2, kc = (t & 3) * 16;
    union { u16 h[16]; short8 s[2]; } Hh, Ll;
#pragma unroll
    for (int j = 0; j < 16; ++j) {
        float x = s_t[kc + j][n];
        Hh.h[j] = f2bf(x);
        Ll.h[j] = f2bf(x - bf2f(Hh.h[j]));
    }
    u16* dh = (zz == 0) ? WqThi : (zz == 1) ? WkThi : (zz == 2) ? WvT : WoT;
    u16* dl = (zz == 0) ? WqTlo : (zz == 1) ? WkTlo : nullptr;
    size_t o = (size_t)(n0 + n) * D_ + k0 + kc;
    *(short8*)(dh + o) = Hh.s[0];
    *(short8*)(dh + o + 8) = Hh.s[1];
    if (dl) {
        *(short8*)(dl + o) = Ll.s[0];
        *(short8*)(dl + o + 8) = Ll.s[1];
    }
}

// ---------------------------------------------------------------------------
// Kernel 1: m97-style 128x128 GEMM, BK=32, global_load_lds staging.
// z = blockIdx.z + zbase:  0=Q (split out, *1/8)  1=K (split out)
//                          2=V (bf16, transposed [B,H,64,T])  3=O (fp32+bias)
// ---------------------------------------------------------------------------
__global__ __launch_bounds__(256) void gemm_kernel(
    const u16* __restrict__ Ahi, const u16* __restrict__ Alo, int zbase,
    const u16* __restrict__ BqH, const u16* __restrict__ BqL,
    const u16* __restrict__ BkH, const u16* __restrict__ BkL,
    const u16* __restrict__ BvT, const u16* __restrict__ BoT,
    const float* __restrict__ bq, const float* __restrict__ bk,
    const float* __restrict__ bv, const float* __restrict__ bo,
    u16* __restrict__ Qhi, u16* __restrict__ Qlo,
    u16* __restrict__ Khi, u16* __restrict__ Klo,
    u16* __restrict__ Vt,  float* __restrict__ outF)
{
    __shared__ u16 sAhi[128 * 32];
    __shared__ u16 sAlo[128 * 32];
    __shared__ u16 sBhi[128 * 32];
    __shared__ u16 sBlo[128 * 32];

    const int z = blockIdx.z + zbase;
    const u16* __restrict__ Bh = (z == 0) ? BqH : (z == 1) ? BkH : (z == 2) ? BvT : BoT;
    const u16* __restrict__ Bl = (z == 0) ? BqL : (z == 1) ? BkL : nullptr;
    const float* __restrict__ bias = (z == 0) ? bq : (z == 1) ? bk : (z == 2) ? bv : bo;
    const bool split = (z < 2);

    const int m0 = blockIdx.y * 128;
    const int n0 = blockIdx.x * 128;
    const int tid = threadIdx.x;
    const int w = tid >> 6, l = tid & 63;
    const int g = l >> 4, lr = l & 15;
    const int wm = w >> 1, wn = w & 1;

    const int srow = w * 32 + (l >> 2);
    const int skb  = (l & 3) * 8;

    f32x4 acc[4][4] = {};

    for (int k0 = 0; k0 < D_; k0 += 32) {
        __syncthreads();
#pragma unroll
        for (int i = 0; i < 2; ++i) {
            gload16(Ahi + (size_t)(m0 + srow + i * 16) * D_ + k0 + skb,
                    &sAhi[w * 1024 + i * 512]);
            gload16(Bh + (size_t)(n0 + srow + i * 16) * D_ + k0 + skb,
                    &sBhi[w * 1024 + i * 512]);
        }
        if (split) {
#pragma unroll
            for (int i = 0; i < 2; ++i) {
                gload16(Alo + (size_t)(m0 + srow + i * 16) * D_ + k0 + skb,
                        &sAlo[w * 1024 + i * 512]);
                gload16(Bl + (size_t)(n0 + srow + i * 16) * D_ + k0 + skb,
                        &sBlo[w * 1024 + i * 512]);
            }
        }
        __syncthreads();

        short8 ah[4], bh[4];
#pragma unroll
        for (int f = 0; f < 4; ++f) {
            ah[f] = *(const short8*)&sAhi[(wm * 64 + f * 16 + lr) * 32 + g * 8];
            bh[f] = *(const short8*)&sBhi[(wn * 64 + f * 16 + lr) * 32 + g * 8];
        }
#pragma unroll
        for (int fm = 0; fm < 4; ++fm)
#pragma unroll
            for (int fn = 0; fn < 4; ++fn)
                acc[fm][fn] = mfma16(ah[fm], bh[fn], acc[fm][fn]);
        if (split) {
            short8 al[4], bl[4];
#pragma unroll
            for (int f = 0; f < 4; ++f) {
                al[f] = *(const short8*)&sAlo[(wm * 64 + f * 16 + lr) * 32 + g * 8];
                bl[f] = *(const short8*)&sBlo[(wn * 64 + f * 16 + lr) * 32 + g * 8];
            }
#pragma unroll
            for (int fm = 0; fm < 4; ++fm)
#pragma unroll
                for (int fn = 0; fn < 4; ++fn) {
                    acc[fm][fn] = mfma16(ah[fm], bl[fn], acc[fm][fn]);
                    acc[fm][fn] = mfma16(al[fm], bh[fn], acc[fm][fn]);
                }
        }
    }

    const float scale = (z == 0) ? 0.125f : 1.0f;
    float biasv[4];
#pragma unroll
    for (int f = 0; f < 4; ++f) biasv[f] = bias[n0 + wn * 64 + f * 16 + lr];

    if (z <= 1) {
        u16* Oh = (z == 0) ? Qhi : Khi;
        u16* Ol = (z == 0) ? Qlo : Klo;
#pragma unroll
        for (int fm = 0; fm < 4; ++fm)
#pragma unroll
            for (int fn = 0; fn < 4; ++fn)
#pragma unroll
                for (int j = 0; j < 4; ++j) {
                    int r = m0 + wm * 64 + fm * 16 + g * 4 + j;
                    int c = n0 + wn * 64 + fn * 16 + lr;
                    float v = (acc[fm][fn][j] + biasv[fn]) * scale;
                    int b = r >> 11, t = r & (T_ - 1);
                    int h = (c >> 6) & 15, d = c & 63;
                    size_t idx = ((size_t)(b * H_ + h) * T_ + t) * DH_ + d;
                    u16 hv = f2bf(v);
                    Oh[idx] = hv;
                    Ol[idx] = f2bf(v - bf2f(hv));
                }
    } else if (z == 2) {
#pragma unroll
        for (int fm = 0; fm < 4; ++fm)
#pragma unroll
            for (int fn = 0; fn < 4; ++fn) {
                int r0 = m0 + wm * 64 + fm * 16 + g * 4;
                int c  = n0 + wn * 64 + fn * 16 + lr;
                int b = r0 >> 11, t0 = r0 & (T_ - 1);
                int h = (c >> 6) & 15, d = c & 63;
                uint2 pk;
                pk.x = (uint32_t)f2bf(acc[fm][fn][0] + biasv[fn]) |
                       ((uint32_t)f2bf(acc[fm][fn][1] + biasv[fn]) << 16);
                pk.y = (uint32_t)f2bf(acc[fm][fn][2] + biasv[fn]) |
                       ((uint32_t)f2bf(acc[fm][fn][3] + biasv[fn]) << 16);
                *(uint2*)&Vt[((size_t)(b * H_ + h) * DH_ + d) * T_ + t0] = pk;
            }
    } else {
#pragma unroll
        for (int fm = 0; fm < 4; ++fm)
#pragma unroll
            for (int fn = 0; fn < 4; ++fn)
#pragma unroll
                for (int j = 0; j < 4; ++j) {
                    int r = m0 + wm * 64 + fm * 16 + g * 4 + j;
                    int c = n0 + wn * 64 + fn * 16 + lr;
                    outF[(size_t)r * D_ + c] = acc[fm][fn][j] + biasv[fn];
                }
    }
}

// ---------------------------------------------------------------------------
// Kernel 2: flash attention, swapped-QK^T 32x32x16, register double-buffered
// K/V/mask prefetch (2 tiles per iteration, named A/B reg sets), XCD-aware
// block swizzle so all 16 q-blocks of one (b,h) share an XCD's L2.
// ---------------------------------------------------------------------------
__device__ __forceinline__ void attn_tile(
    const short8* kh, const short8* kl, const short8* vb, uint32_t mw,
    const short8* qfh, const short8* qfl,
    f32x16& o0, f32x16& o1, float& m_run, float& l_run)
{
    const float L2E = 1.4426950408889634f;
    f32x16 s = {};
    __builtin_amdgcn_s_setprio(1);
#pragma unroll
    for (int c = 0; c < 4; ++c) {
        s = mfma32(kh[c], qfh[c], s);
        s = mfma32(kh[c], qfl[c], s);
        s = mfma32(kl[c], qfh[c], s);
    }
    __builtin_amdgcn_s_setprio(0);

#pragma unroll
    for (int r = 0; r < 16; ++r) {
        const int bit = (r & 3) + 8 * (r >> 2);
        if (!((mw >> bit) & 1u)) s[r] = -1e30f;
    }

    float pm = s[0];
#pragma unroll
    for (int r = 1; r < 16; ++r) pm = fmaxf(pm, s[r]);
    pm = fmaxf(pm, __shfl_xor(pm, 32));

    if (__any(pm > m_run + 8.0f)) {        // defer-max rescale (T13)
        float mn  = fmaxf(m_run, pm);
        float fac = exp2f((m_run - mn) * L2E);
        l_run *= fac;
#pragma unroll
        for (int r = 0; r < 16; ++r) { o0[r] *= fac; o1[r] *= fac; }
        m_run = mn;
    }

    float p[16]; float sum = 0.0f;
#pragma unroll
    for (int r = 0; r < 16; ++r) {
        p[r] = exp2f((s[r] - m_run) * L2E);
        sum += p[r];
    }
    sum += __shfl_xor(sum, 32);
    l_run += sum;

    uint32_t wv[8];
#pragma unroll
    for (int m2 = 0; m2 < 8; ++m2)
        asm("v_cvt_pk_bf16_f32 %0, %1, %2"
            : "=v"(wv[m2]) : "v"(p[2 * m2]), "v"(p[2 * m2 + 1]));
    asm("v_permlane32_swap_b32 %0, %1" : "+v"(wv[0]), "+v"(wv[2]));
    asm("v_permlane32_swap_b32 %0, %1" : "+v"(wv[1]), "+v"(wv[3]));
    asm("v_permlane32_swap_b32 %0, %1" : "+v"(wv[4]), "+v"(wv[6]));
    asm("v_permlane32_swap_b32 %0, %1" : "+v"(wv[5]), "+v"(wv[7]));
    union { uint32_t u[4]; short8 s8; } pa1, pa2;
    pa1.u[0] = wv[0]; pa1.u[1] = wv[1]; pa1.u[2] = wv[2]; pa1.u[3] = wv[3];
    pa2.u[0] = wv[4]; pa2.u[1] = wv[5]; pa2.u[2] = wv[6]; pa2.u[3] = wv[7];

    __builtin_amdgcn_s_setprio(1);
    o0 = mfma32(vb[0], pa1.s8, o0);
    o0 = mfma32(vb[1], pa2.s8, o0);
    o1 = mfma32(vb[2], pa1.s8, o1);
    o1 = mfma32(vb[3], pa2.s8, o1);
    __builtin_amdgcn_s_setprio(0);
}

#define LOAD_TILE(kh, kl, vb, mw, kv)                                          \
    do {                                                                       \
        _Pragma("unroll")                                                      \
        for (int c = 0; c < 4; ++c) {                                          \
            kh[c] = *(const short8*)&Kh[(size_t)((kv) + qi) * DH_ + c * 16 + hl * 8]; \
            kl[c] = *(const short8*)&Kl[(size_t)((kv) + qi) * DH_ + c * 16 + hl * 8]; \
        }                                                                      \
        vb[0] = *(const short8*)&Vh[(size_t)(qi) * T_ + (kv) + hl * 8];        \
        vb[1] = *(const short8*)&Vh[(size_t)(qi) * T_ + (kv) + 16 + hl * 8];   \
        vb[2] = *(const short8*)&Vh[(size_t)(32 + qi) * T_ + (kv) + hl * 8];   \
        vb[3] = *(const short8*)&Vh[(size_t)(32 + qi) * T_ + (kv) + 16 + hl * 8]; \
        mw = mrow[(kv) >> 5] >> (hl * 4);                                      \
    } while (0)

__global__ __launch_bounds__(256, 2) void attn2_kernel(
    const u16* __restrict__ Qhi, const u16* __restrict__ Qlo,
    const u16* __restrict__ Khi, const u16* __restrict__ Klo,
    const u16* __restrict__ Vt,  const uint32_t* __restrict__ bits,
    u16* __restrict__ comb)
{
    // XCD swizzle: all 16 qb-blocks of one bh get the same bx%8 (same XCD
    // under round-robin dispatch).  Bijective on [0,512).
    const int bx  = blockIdx.x;
    const int bh  = (bx & 7) + 8 * (bx >> 7);
    const int qb  = (bx >> 3) & 15;
    const int b   = bh >> 4, h = bh & 15;
    const int tid = threadIdx.x;
    const int w   = tid >> 6;
    const int l   = tid & 63;
    const int qi  = l & 31;
    const int hl  = l >> 5;
    const int q   = qb * 128 + w * 32 + qi;

    const size_t hoff = (size_t)(b * H_ + h) * T_ * DH_;
    const u16* Qh = Qhi + hoff;
    const u16* Ql = Qlo + hoff;
    const u16* Kh = Khi + hoff;
    const u16* Kl = Klo + hoff;
    const u16* Vh = Vt  + hoff;                        // [64][T]
    const uint32_t* mrow = bits + ((size_t)b * T_ + q) * (T_ / 32);

    short8 qfh[4], qfl[4];
#pragma unroll
    for (int c = 0; c < 4; ++c) {
        qfh[c] = *(const short8*)&Qh[(size_t)q * DH_ + c * 16 + hl * 8];
        qfl[c] = *(const short8*)&Ql[(size_t)q * DH_ + c * 16 + hl * 8];
    }

    f32x16 o0 = {}; f32x16 o1 = {};
    float m_run = -1e30f, l_run = 0.0f;

    short8 khA[4], klA[4], vbA[4]; uint32_t mwA;
    short8 khB[4], klB[4], vbB[4]; uint32_t mwB;

    LOAD_TILE(khA, klA, vbA, mwA, 0);

    for (int kv0 = 0; kv0 < T_; kv0 += 64) {
        LOAD_TILE(khB, klB, vbB, mwB, kv0 + 32);
        attn_tile(khA, klA, vbA, mwA, qfh, qfl, o0, o1, m_run, l_run);
        LOAD_TILE(khA, klA, vbA, mwA, (kv0 + 64) & (T_ - 1));   // wraps on last
        attn_tile(khB, klB, vbB, mwB, qfh, qfl, o0, o1, m_run, l_run);
    }

    float inv = 1.0f / l_run;
    float ov[32];
#pragma unroll
    for (int r = 0; r < 16; ++r) { ov[r] = o0[r]; ov[16 + r] = o1[r]; }
    u16* crow = comb + (size_t)(b * T_ + q) * D_ + h * DH_;
#pragma unroll
    for (int dt = 0; dt < 2; ++dt)
#pragma unroll
        for (int g2 = 0; g2 < 4; ++g2) {
            float v0 = ov[dt * 16 + 4 * g2 + 0] * inv;
            float v1 = ov[dt * 16 + 4 * g2 + 1] * inv;
            float v2 = ov[dt * 16 + 4 * g2 + 2] * inv;
            float v3 = ov[dt * 16 + 4 * g2 + 3] * inv;
            uint2 pkt;
            pkt.x = (uint32_t)f2bf(v0) | ((uint32_t)f2bf(v1) << 16);
            pkt.y = (uint32_t)f2bf(v2) | ((uint32_t)f2bf(v3) << 16);
            *(uint2*)(crow + dt * 32 + 8 * g2 + 4 * hl) = pkt;
        }
}

// ---------------------------------------------------------------------------
extern "C" void kernel_launch(void* const* d_in, const int* in_sizes, int n_in,
                              void* d_out, int out_size, void* d_ws, size_t ws_size,
                              hipStream_t stream)
{
    const float* X    = (const float*)d_in[0];
    const int*   mask = (const int*)d_in[1];
    const float* Wq   = (const float*)d_in[2];
    const float* bq   = (const float*)d_in[3];
    const float* Wk   = (const float*)d_in[4];
    const float* bk   = (const float*)d_in[5];
    const float* Wv   = (const float*)d_in[6];
    const float* bv   = (const float*)d_in[7];
    const float* Wo   = (const float*)d_in[8];
    const float* bo   = (const float*)d_in[9];
    float* out = (float*)d_out;

    const size_t SEG = (size_t)B_ * H_ * T_ * DH_;   // = B*T*D elems
    const size_t WSEG = (size_t)D_ * D_;
    u16* wsp = (u16*)d_ws;
    u16* Qhi   = wsp + 0 * SEG;
    u16* Qlo   = wsp + 1 * SEG;
    u16* Khi   = wsp + 2 * SEG;
    u16* Klo   = wsp + 3 * SEG;
    u16* Xhi   = wsp + 4 * SEG;        // aliased: comb (attn output) after GEMMs
    u16* Xlo   = wsp + 5 * SEG;
    u16* WqThi = wsp + 6 * SEG;
    u16* WqTlo = WqThi + WSEG;
    u16* WkThi = WqThi + 2 * WSEG;
    u16* WkTlo = WqThi + 3 * WSEG;
    u16* WvT   = WqThi + 4 * WSEG;
    u16* WoT   = WqThi + 5 * WSEG;
    u16* comb  = Xhi;
    u16* Vt = (u16*)d_out;
    uint32_t* bits = (uint32_t*)((char*)d_out + (8u << 20));

    dim3 blk(256);
    maskpack_kernel<<<dim3((B_ * T_ * T_) / 256), blk, 0, stream>>>(mask, bits);
    splitx_kernel<<<dim3((B_ * T_ * D_) / 2048), blk, 0, stream>>>(X, Xhi, Xlo);
    wtr_kernel<<<dim3(16, 16, 4), blk, 0, stream>>>(
        Wq, Wk, Wv, Wo, WqThi, WqTlo, WkThi, WkTlo, WvT, WoT);
    gemm_kernel<<<dim3(D_ / 128, (B_ * T_) / 128, 3), blk, 0, stream>>>(
        Xhi, Xlo, 0, WqThi, WqTlo, WkThi, WkTlo, WvT, WoT,
        bq, bk, bv, bo, Qhi, Qlo, Khi, Klo, Vt, out);
    attn2_kernel<<<dim3(B_ * H_ * (T_ / 128)), blk, 0, stream>>>(
        Qhi, Qlo, Khi, Klo, Vt, bits, comb);
    gemm_kernel<<<dim3(D_ / 128, (B_ * T_) / 128, 1), blk, 0, stream>>>(
        comb, nullptr, 3, WqThi, WqTlo, WkThi, WkTlo, WvT, WoT,
        bq, bk, bv, bo, Qhi, Qlo, Khi, Klo, Vt, out);
}